// Round 14
// baseline (91.756 us; speedup 1.0000x reference)
//
#include <hip/hip_runtime.h>
#include <math.h>

#define BG    128                      // graphs (B)
#define NN    40                       // nodes per graph
#define AK    32                       // K (mixture comps)
#define ZD    32                       // Z latent dim
#define HIDN  256                      // HID
#define ETAD  64                       // ETA
#define NATOM 24
#define NBOND 5
#define NA    (BG*NN)                  // 5120 nodes
#define EPG   (NN*(NN-1)/2)            // 780 edges per graph
#define NE    (BG*EPG)                 // 99840 edges

typedef __attribute__((ext_vector_type(8))) short bf16x8;
typedef __attribute__((ext_vector_type(4))) float f32x4;

__device__ __forceinline__ unsigned short f2bf(float f) {
    union { float f; unsigned int u; } x; x.f = f;
    unsigned int r = x.u + 0x7fffu + ((x.u >> 16) & 1u);   // RNE
    return (unsigned short)(r >> 16);
}
__device__ __forceinline__ unsigned int pk2bf(float lo, float hi) {
    return (unsigned int)f2bf(lo) | ((unsigned int)f2bf(hi) << 16);
}

// ================= k_pre: all weight packs + class hidden + zero accums ==========
__global__ __launch_bounds__(256) void k_pre(const float* __restrict__ bm,
                                             const float* __restrict__ bw1,
                                             const float* __restrict__ aw1,
                                             const float* __restrict__ aw2,
                                             const float* __restrict__ eta,
                                             const float* __restrict__ cw1,
                                             const float* __restrict__ cb1,
                                             unsigned short* __restrict__ wmpk,
                                             unsigned short* __restrict__ bpack,
                                             unsigned short* __restrict__ apk1,
                                             unsigned short* __restrict__ apk2,
                                             float* __restrict__ h1,
                                             float* __restrict__ cpart,
                                             float* __restrict__ zacc) {
    int b = blockIdx.x, t = threadIdx.x;
    if (b < 128) {          // symmetrized Wm -> A-frag bf16
        int idx = b*256 + t;
        int d = idx >> 10;
        int Bt = (idx >> 9) & 1, ln = (idx >> 3) & 63, j = idx & 7;
        int al = Bt*16 + (ln & 15);
        int be = (ln >> 4)*8 + j;
        float v = 0.5f * (bm[d*1024 + al*32 + be] + bm[d*1024 + be*32 + al]);
        wmpk[idx] = f2bf(v);
    } else if (b < 160) {   // bw1 -> B-frag bf16
        int idx = (b - 128)*256 + t;
        int ct = idx >> 9, rem = idx & 511;
        int lane = rem >> 3, j = rem & 7;
        bpack[idx] = f2bf(bw1[((lane >> 4)*8 + j)*HIDN + ct*16 + (lane & 15)]);
    } else if (b < 192) {   // aw1 -> B-frag bf16
        int idx = (b - 160)*256 + t;
        int ct = idx >> 9, rem = idx & 511;
        int lane = rem >> 3, j = rem & 7;
        apk1[idx] = f2bf(aw1[((lane >> 4)*8 + j)*HIDN + ct*16 + (lane & 15)]);
    } else if (b < 224) {   // aw2 -> B-frag bf16 (24 cols zero-padded to 32)
        int idx = (b - 192)*256 + t;
        int f = idx >> 9, rem = idx & 511;
        int lane = rem >> 3, j = rem & 7;
        int kc = f >> 1, ot = f & 1;
        int col = ot*16 + (lane & 15);
        int k = kc*32 + (lane >> 4)*8 + j;
        apk2[idx] = (col < NATOM) ? f2bf(aw2[k*NATOM + col]) : 0;
    } else if (b < 232) {   // class h1 rows b2*16..+15, per-block stat partials
        __shared__ float es[16*ETAD];
        int b2 = b - 224;
        int r0 = b2*16;
        for (int i = t; i < 16*ETAD; i += 256) es[i] = eta[r0*ETAD + i];
        __syncthreads();
        int c = t;
        float bias = cb1[c], s = 0.f, ss = 0.f;
        for (int r = 0; r < 16; ++r) {
            float acc = bias;
#pragma unroll
            for (int a = 0; a < ETAD; ++a) acc += es[r*ETAD + a] * cw1[a*HIDN + c];
            h1[(r0 + r)*HIDN + c] = acc;
            s += acc; ss += acc*acc;
        }
        cpart[b2*512 + c] = s;
        cpart[b2*512 + 256 + c] = ss;
    } else {                // zero mom_z + mom_ef
        for (int i = t; i < 2112; i += 256) zacc[i] = 0.f;
    }
}

// ===== fused class path + edge featurizer ========================================
// ef layout: seg-major efb[(seg*NE + e)*8 + (a&7)], seg = a>>3  -> contiguous flush.
__global__ __launch_bounds__(256) void k_edge_class(const float* __restrict__ h1,
                                                    const float* __restrict__ cpart,
                                                    const float* __restrict__ cg,
                                                    const float* __restrict__ cbe,
                                                    const float* __restrict__ ca,
                                                    const float* __restrict__ cw2,
                                                    const float* __restrict__ cb2,
                                                    const float* __restrict__ gum,
                                                    const float* __restrict__ noise,
                                                    const float* __restrict__ cm,
                                                    const float* __restrict__ cls,
                                                    const unsigned short* __restrict__ wmpk,
                                                    float* __restrict__ z,
                                                    float* __restrict__ mom_z,
                                                    float* __restrict__ ef) {
    __shared__ float zl[NN*36];                 // 5760 B
    __shared__ float p[HIDN];
    __shared__ float vp2[256];
    __shared__ float oo[AK];
    __shared__ float lp[AK];
    __shared__ unsigned short zfrag[3*512];     // 3 KB
    __shared__ unsigned short Tf[4][3*512];     // 12 KB
    __shared__ float efl[EPG*9];                // 28 KB
    int t = threadIdx.x;
    int g = blockIdx.x >> 2, dg = blockIdx.x & 3;
    float aP = ca[0];

    // ---- class BN + W2 + log_softmax ----
    {
        float s = 0.f, ss = 0.f;
#pragma unroll
        for (int q = 0; q < 8; ++q) { s += cpart[q*512 + t]; ss += cpart[q*512 + 256 + t]; }
        float m = s * (1.0f/(float)BG);
        float v = ss * (1.0f/(float)BG) - m*m;
        float x = h1[g*HIDN + t];
        float xn = (x - m) * (1.0f/sqrtf(v + 1e-5f)) * cg[t] + cbe[t];
        p[t] = xn >= 0.f ? xn : aP*xn;
    }
    __syncthreads();
    {
        int k = t & 31, part = t >> 5;
        float acc = 0.f;
        const float* pc = &p[part*32];
        const float* wc = &cw2[(part*32)*AK + k];
#pragma unroll
        for (int c = 0; c < 32; ++c) acc += pc[c] * wc[c*AK];
        vp2[t] = acc;
    }
    __syncthreads();
    if (t < AK) {
        float acc = cb2[t];
#pragma unroll
        for (int q = 0; q < 8; ++q) acc += vp2[q*32 + t];
        oo[t] = acc;
    }
    __syncthreads();
    if (t < AK) {
        float m = -INFINITY;
#pragma unroll
        for (int k = 0; k < AK; ++k) m = fmaxf(m, oo[k]);
        float S = 0.f;
#pragma unroll
        for (int k = 0; k < AK; ++k) S += expf(oo[k] - m);
        lp[t] = oo[t] - m - logf(S);
    }
    __syncthreads();
    // ---- gumbel + z (all blocks compute; only dg==0 writes global) ----
    {
        int lane = t & 31;
#pragma unroll
        for (int nb = 0; nb < 5; ++nb) {
            int node = nb*8 + (t >> 5);
            int n = g*NN + node;
            float u = gum[(size_t)n*AK + lane];
            float x = lp[lane] - logf(-logf(u));       // TAU == 1
            float m = x;
#pragma unroll
            for (int s = 1; s < 32; s <<= 1) m = fmaxf(m, __shfl_xor(m, s, 32));
            float e = expf(x - m);
            float S = e;
#pragma unroll
            for (int s = 1; s < 32; s <<= 1) S += __shfl_xor(S, s, 32);
            unsigned long long bal = __ballot(x == m);
            unsigned grp = (unsigned)(bal >> (t & 32));
            int am = __ffs(grp) - 1;
            float best = 1.0f / S;                     // y_soft at argmax
            float cam = (1.0f - best) + best;          // exact fp replication
            float ls = cam * cls[am*ZD + lane];
            ls = fminf(fmaxf(ls, -20.0f), 30.0f);
            float zv = noise[(size_t)n*ZD + lane]*expf(ls) + cam*cm[am*ZD + lane];
            zl[node*36 + lane] = zv;
            if (dg == 0) z[(size_t)n*ZD + lane] = zv;
        }
    }
    __syncthreads();
    // ---- z-moment partials (dg==0 only) ----
    if (dg == 0) {
        int a = t >> 3, b4 = (t & 7) << 2;
        float ax = 0.f, ay = 0.f, az = 0.f, aw = 0.f;
        float mx = 0.f, my = 0.f, mz = 0.f, mw = 0.f;
        for (int r = 0; r < NN; ++r) {
            float  va = zl[r*36 + a];
            float4 vb = *(const float4*)&zl[r*36 + b4];
            ax += va*vb.x; ay += va*vb.y; az += va*vb.z; aw += va*vb.w;
            mx += vb.x;    my += vb.y;    mz += vb.z;    mw += vb.w;
        }
        atomicAdd(&mom_z[a*ZD + b4 + 0], ax);
        atomicAdd(&mom_z[a*ZD + b4 + 1], ay);
        atomicAdd(&mom_z[a*ZD + b4 + 2], az);
        atomicAdd(&mom_z[a*ZD + b4 + 3], aw);
        if (a == 0) {
            atomicAdd(&mom_z[ZD*ZD + b4 + 0], mx);
            atomicAdd(&mom_z[ZD*ZD + b4 + 1], my);
            atomicAdd(&mom_z[ZD*ZD + b4 + 2], mz);
            atomicAdd(&mom_z[ZD*ZD + b4 + 3], mw);
        }
    }
    // ---- build z MFMA frags straight from LDS ----
    if (t < 192) {
        int I = t >> 6, ln = t & 63;
        int row = I*16 + (ln & 15), c0 = (ln >> 4)*8;
        unsigned int pk[4] = {0u, 0u, 0u, 0u};
        if (row < NN) {
            float4 v0 = *(const float4*)&zl[row*36 + c0];
            float4 v1 = *(const float4*)&zl[row*36 + c0 + 4];
            pk[0] = pk2bf(v0.x, v0.y); pk[1] = pk2bf(v0.z, v0.w);
            pk[2] = pk2bf(v1.x, v1.y); pk[3] = pk2bf(v1.z, v1.w);
        }
        *(uint4*)&zfrag[(I*64 + ln)*8] = make_uint4(pk[0], pk[1], pk[2], pk[3]);
    }
    __syncthreads();

    // ---- edge featurizer via MFMA (G = Z Wsym Z^T) ----
    int w = t >> 6, lane = t & 63;
    int l15 = lane & 15, gq = lane >> 4;
    f32x4 zero4 = {0.f, 0.f, 0.f, 0.f};

    bf16x8 zf[3];
#pragma unroll
    for (int I = 0; I < 3; ++I) zf[I] = *(const bf16x8*)&zfrag[I*512 + lane*8];

    for (int dk = 0; dk < 2; ++dk) {
        int dd = w*2 + dk;
        int d  = dg*8 + dd;
        bf16x8 wA[2];
        wA[0] = *(const bf16x8*)&wmpk[(d*2 + 0)*512 + lane*8];
        wA[1] = *(const bf16x8*)&wmpk[(d*2 + 1)*512 + lane*8];

        unsigned short* tw = &Tf[w][0];
        int gqp_lo = (gq >> 1);
        int jo     = (gq & 1)*4;
#pragma unroll
        for (int Bt = 0; Bt < 2; ++Bt) {
#pragma unroll
            for (int I = 0; I < 3; ++I) {
                f32x4 c = __builtin_amdgcn_mfma_f32_16x16x32_bf16(wA[Bt], zf[I], zero4, 0, 0, 0);
                int gqp = Bt*2 + gqp_lo;
                int pos = I*512 + gqp*128 + l15*8 + jo;
                unsigned int d0 = pk2bf(c[0], c[1]);
                unsigned int d1 = pk2bf(c[2], c[3]);
                *(uint2*)&tw[pos] = make_uint2(d0, d1);
            }
        }
        __syncthreads();

        bf16x8 tf[3];
#pragma unroll
        for (int J = 0; J < 3; ++J) tf[J] = *(const bf16x8*)&Tf[w][J*512 + lane*8];

#pragma unroll
        for (int I = 0; I < 3; ++I) {
#pragma unroll
            for (int J = I; J < 3; ++J) {
                f32x4 gacc = __builtin_amdgcn_mfma_f32_16x16x32_bf16(zf[I], tf[J], zero4, 0, 0, 0);
                int j = J*16 + l15;
                if (j < NN) {
#pragma unroll
                    for (int r = 0; r < 4; ++r) {
                        int i = I*16 + 4*gq + r;
                        if (i < j) {
                            int e = i*(79 - i)/2 + (j - i - 1);
                            efl[e*9 + dd] = gacc[r];
                        }
                    }
                }
            }
        }
        __syncthreads();
    }

    // contiguous flush: this block owns efb rows [dg*NE + g*EPG, +EPG) x 8
    size_t base = ((size_t)dg*NE + (size_t)g*EPG)*8;
    for (int idx = t; idx < EPG*8; idx += 256) {
        int e = idx >> 3, dd = idx & 7;
        ef[base + idx] = efl[e*9 + dd];
    }
}

// ===== ef moments via MFMA (blocks 0-191) + atom BN-prep (block 192) =============
#define MOMB 192
__global__ __launch_bounds__(256) void k_moment(const float* __restrict__ src,
                                                float* __restrict__ mom,
                                                const float* __restrict__ mom_z,
                                                const float* __restrict__ aw1,
                                                const float* __restrict__ ab1,
                                                const float* __restrict__ ag,
                                                const float* __restrict__ abe,
                                                float* __restrict__ ascale,
                                                float* __restrict__ ashift,
                                                int nchunks) {
    __shared__ float sm[ZD*ZD + ZD];   // 1056 floats (also cov+mean for prep)
    int t = threadIdx.x;

    if (blockIdx.x == MOMB) {
        // atom BN-prep: mom_z complete (k_edge_class finished) -> plain loads
        float* cov = sm;
        float* mean = sm + ZD*ZD;
        if (t < ZD) mean[t] = mom_z[ZD*ZD + t] * (1.0f/(float)NA);
        __syncthreads();
        for (int pp = t; pp < ZD*ZD; pp += 256) {
            int a = pp >> 5, b = pp & 31;
            cov[pp] = mom_z[pp] * (1.0f/(float)NA) - mean[a]*mean[b];
        }
        __syncthreads();
        int c = t;
        float wr[ZD];
#pragma unroll
        for (int b = 0; b < ZD; ++b) wr[b] = aw1[b*HIDN + c];
        float var = 0.f, mh = 0.f;
        for (int a = 0; a < ZD; ++a) {
            float tmp = 0.f;
            const float4* cr = (const float4*)&cov[a*ZD];
#pragma unroll
            for (int b4 = 0; b4 < 8; ++b4) {
                float4 cv = cr[b4];
                tmp += cv.x*wr[b4*4] + cv.y*wr[b4*4+1] + cv.z*wr[b4*4+2] + cv.w*wr[b4*4+3];
            }
            var += tmp * wr[a];
            mh  += mean[a] * wr[a];
        }
        mh += ab1[c];
        float rs = rsqrtf(fmaxf(var, 0.f) + 1e-5f) * ag[c];
        ascale[c] = rs;
        ashift[c] = abe[c] - mh * rs;
        return;
    }

    for (int i = t; i < ZD*ZD + ZD; i += 256) sm[i] = 0.f;
    __syncthreads();
    int lane = t & 63, wv = t >> 6;
    int l15 = lane & 15, g4 = lane >> 4;
    int wgid = blockIdx.x * 4 + wv;
    const int nw = MOMB * 4;
    f32x4 aII = {0,0,0,0}, aIJ = {0,0,0,0}, aJI = {0,0,0,0}, aJJ = {0,0,0,0};
    float mI = 0.f, mJ = 0.f;
    // seg-major ef: row r, comp a -> src[((a>>3)*NE + r)*8 + (a&7)]
    int segI = l15 >> 3, offI = l15 & 7;
    for (int ch = wgid; ch < nchunks; ch += nw) {
        size_t br = (size_t)ch*32 + g4*8;
        const float* pI = src + ((size_t)segI*NE + br)*8 + offI;
        const float* pJ = src + ((size_t)(2 + segI)*NE + br)*8 + offI;
        float vI[8], vJ[8];
#pragma unroll
        for (int j = 0; j < 8; ++j) { vI[j] = pI[j*8]; vJ[j] = pJ[j*8]; }
        bf16x8 fI, fJ;
#pragma unroll
        for (int j = 0; j < 8; ++j) {
            fI[j] = (short)f2bf(vI[j]); fJ[j] = (short)f2bf(vJ[j]);
            mI += vI[j]; mJ += vJ[j];
        }
        aII = __builtin_amdgcn_mfma_f32_16x16x32_bf16(fI, fI, aII, 0, 0, 0);
        aIJ = __builtin_amdgcn_mfma_f32_16x16x32_bf16(fI, fJ, aIJ, 0, 0, 0);
        aJI = __builtin_amdgcn_mfma_f32_16x16x32_bf16(fJ, fI, aJI, 0, 0, 0);
        aJJ = __builtin_amdgcn_mfma_f32_16x16x32_bf16(fJ, fJ, aJJ, 0, 0, 0);
    }
#pragma unroll
    for (int r = 0; r < 4; ++r) {
        int row = g4*4 + r;
        atomicAdd(&sm[row*ZD + l15],             aII[r]);
        atomicAdd(&sm[row*ZD + 16 + l15],        aIJ[r]);
        atomicAdd(&sm[(16 + row)*ZD + l15],      aJI[r]);
        atomicAdd(&sm[(16 + row)*ZD + 16 + l15], aJJ[r]);
    }
    atomicAdd(&sm[ZD*ZD + l15], mI);
    atomicAdd(&sm[ZD*ZD + 16 + l15], mJ);
    __syncthreads();
    for (int i = t; i < ZD*ZD + ZD; i += 256) atomicAdd(&mom[i], sm[i]);
}

// ====== fused output: blocks 0-79 atom MLP, blocks 80-859 bond MLP ===============
// Bond blocks compute their BN scale/shift in-block from mom_ef (redundant,
// parallel). b1 terms cancel: shift = bbe - (w^T mean)*rs.
#define PSH 264        // halfword stride: 528B -> 2-way max on frag reads (free)
#define ATOMB (NA/64)  // 80
#define BROWS4 128
__global__ __launch_bounds__(256) void k_out(const float* __restrict__ z,
                                             const unsigned short* __restrict__ apk1,
                                             const unsigned short* __restrict__ apk2,
                                             const float* __restrict__ ab1,
                                             const float* __restrict__ ascale,
                                             const float* __restrict__ ashift,
                                             const float* __restrict__ aa,
                                             const float* __restrict__ ab2,
                                             const float* __restrict__ ef,
                                             const unsigned short* __restrict__ bpack,
                                             const float* __restrict__ mom_ef,
                                             const float* __restrict__ bw1,
                                             const float* __restrict__ bg,
                                             const float* __restrict__ bbe,
                                             const float* __restrict__ ba,
                                             const float* __restrict__ bw2,
                                             const float* __restrict__ bb2,
                                             float* __restrict__ out_atom,
                                             float* __restrict__ out_bond) {
    __shared__ unsigned short smu[4*16*PSH];   // 33.8 KB union
    int t = threadIdx.x;
    int w = t >> 6, lane = t & 63;
    int l15 = lane & 15, gq = lane >> 4;
    f32x4 zero4 = {0.f, 0.f, 0.f, 0.f};

    if (blockIdx.x < ATOMB) {
        // ---------------- atom path: double MFMA, wave-private LDS ----------------
        size_t r0 = (size_t)blockIdx.x * 64 + (size_t)w * 16;
        float aP = aa[0];
        unsigned short* ptw = &smu[w*16*PSH];

        const float* zp = &z[(r0 + l15)*ZD + gq*8];
        float4 z0 = *(const float4*)zp;
        float4 z1 = *(const float4*)(zp + 4);
        bf16x8 af;
        af[0] = (short)f2bf(z0.x); af[1] = (short)f2bf(z0.y);
        af[2] = (short)f2bf(z0.z); af[3] = (short)f2bf(z0.w);
        af[4] = (short)f2bf(z1.x); af[5] = (short)f2bf(z1.y);
        af[6] = (short)f2bf(z1.z); af[7] = (short)f2bf(z1.w);

#pragma unroll
        for (int ct = 0; ct < 16; ++ct) {
            bf16x8 bf = *(const bf16x8*)&apk1[ct*512 + lane*8];
            f32x4 c = __builtin_amdgcn_mfma_f32_16x16x32_bf16(af, bf, zero4, 0, 0, 0);
            int ch = ct*16 + l15;
            float sc = ascale[ch];
            float sh = ashift[ch] + ab1[ch]*sc;
#pragma unroll
            for (int r = 0; r < 4; ++r) {
                float xn = c[r]*sc + sh;
                float pv = xn >= 0.f ? xn : aP*xn;
                ptw[(4*gq + r)*PSH + ch] = f2bf(pv);
            }
        }
        // wave-private LDS: compiler lgkmcnt waits suffice, no barrier

        f32x4 o0 = zero4, o1 = zero4;
#pragma unroll
        for (int kc = 0; kc < 8; ++kc) {
            bf16x8 af2 = *(const bf16x8*)&ptw[l15*PSH + kc*32 + gq*8];
            bf16x8 b0 = *(const bf16x8*)&apk2[(kc*2 + 0)*512 + lane*8];
            bf16x8 b1 = *(const bf16x8*)&apk2[(kc*2 + 1)*512 + lane*8];
            o0 = __builtin_amdgcn_mfma_f32_16x16x32_bf16(af2, b0, o0, 0, 0, 0);
            o1 = __builtin_amdgcn_mfma_f32_16x16x32_bf16(af2, b1, o1, 0, 0, 0);
        }
#pragma unroll
        for (int r = 0; r < 4; ++r) {
            size_t row = r0 + 4*gq + r;
            out_atom[row*NATOM + l15] = o0[r] + ab2[l15];
            if (l15 < 8) out_atom[row*NATOM + 16 + l15] = o1[r] + ab2[16 + l15];
        }
        return;
    }

    // ---------------- bond path ----------------
    float* w2s  = (float*)smu;          // 1280
    float* scs  = w2s + HIDN*NBOND;     // 256
    float* shs  = scs + HIDN;           // 256
    float* mean = shs + HIDN;           // 32
    float* cov  = mean + 32;            // 1024   (total 11392 B < union)
    size_t r0 = (size_t)(blockIdx.x - ATOMB) * BROWS4;

    for (int i = t; i < HIDN*NBOND; i += 256) w2s[i] = bw2[i];
    if (t < ZD) mean[t] = mom_ef[ZD*ZD + t] * (1.0f/(float)NE);
    __syncthreads();
    for (int pp = t; pp < ZD*ZD; pp += 256) {
        int a = pp >> 5, bb = pp & 31;
        cov[pp] = mom_ef[pp] * (1.0f/(float)NE) - mean[a]*mean[bb];
    }
    __syncthreads();
    {   // in-block BN prep for channel t (b1 cancels in shift)
        int c = t;
        float wr[ZD];
#pragma unroll
        for (int bb = 0; bb < ZD; ++bb) wr[bb] = bw1[bb*HIDN + c];
        float var = 0.f, mh = 0.f;
        for (int a = 0; a < ZD; ++a) {
            float tmp = 0.f;
            const float4* cr = (const float4*)&cov[a*ZD];
#pragma unroll
            for (int b4 = 0; b4 < 8; ++b4) {
                float4 cv = cr[b4];
                tmp += cv.x*wr[b4*4] + cv.y*wr[b4*4+1] + cv.z*wr[b4*4+2] + cv.w*wr[b4*4+3];
            }
            var += tmp * wr[a];
            mh  += mean[a] * wr[a];
        }
        float rs = rsqrtf(fmaxf(var, 0.f) + 1e-5f) * bg[c];
        scs[c] = rs;
        shs[c] = bbe[c] - mh * rs;
    }
    __syncthreads();

    float aP = ba[0];
    float b2r[NBOND];
#pragma unroll
    for (int k = 0; k < NBOND; ++k) b2r[k] = bb2[k];

#pragma unroll
    for (int rt = 0; rt < 2; ++rt) {
        size_t rowt = r0 + (size_t)(w*2 + rt)*16;
        // seg-major ef: seg = gq, contiguous 8 floats per row
        const float* ar = &ef[((size_t)gq*NE + rowt + l15)*8];
        float4 a0 = *(const float4*)ar;
        float4 a1 = *(const float4*)(ar + 4);
        bf16x8 af;
        af[0] = (short)f2bf(a0.x); af[1] = (short)f2bf(a0.y);
        af[2] = (short)f2bf(a0.z); af[3] = (short)f2bf(a0.w);
        af[4] = (short)f2bf(a1.x); af[5] = (short)f2bf(a1.y);
        af[6] = (short)f2bf(a1.z); af[7] = (short)f2bf(a1.w);

        float part[4][NBOND];
#pragma unroll
        for (int r = 0; r < 4; ++r)
#pragma unroll
            for (int k = 0; k < NBOND; ++k) part[r][k] = 0.f;

#pragma unroll
        for (int h = 0; h < 2; ++h) {
            bf16x8 bfr[8];
#pragma unroll
            for (int q = 0; q < 8; ++q)
                bfr[q] = *(const bf16x8*)&bpack[(h*8 + q)*512 + lane*8];
            f32x4 acc[8];
#pragma unroll
            for (int q = 0; q < 8; ++q)
                acc[q] = __builtin_amdgcn_mfma_f32_16x16x32_bf16(af, bfr[q], zero4, 0, 0, 0);
#pragma unroll
            for (int q = 0; q < 8; ++q) {
                int c = (h*8 + q)*16 + l15;
                float sc = scs[c], sh = shs[c];
                float w0 = w2s[c*NBOND+0], w1v = w2s[c*NBOND+1], w2v = w2s[c*NBOND+2];
                float w3 = w2s[c*NBOND+3], w4 = w2s[c*NBOND+4];
#pragma unroll
                for (int r = 0; r < 4; ++r) {
                    float xn = acc[q][r]*sc + sh;
                    float pv = xn >= 0.f ? xn : aP*xn;
                    part[r][0] += pv*w0; part[r][1] += pv*w1v; part[r][2] += pv*w2v;
                    part[r][3] += pv*w3; part[r][4] += pv*w4;
                }
            }
        }

#pragma unroll
        for (int s = 1; s < 16; s <<= 1) {
#pragma unroll
            for (int r = 0; r < 4; ++r)
#pragma unroll
                for (int k = 0; k < NBOND; ++k)
                    part[r][k] += __shfl_xor(part[r][k], s, 64);
        }

        if (l15 == 0) {
#pragma unroll
            for (int r = 0; r < 4; ++r) {
                size_t row = rowt + gq*4 + r;
                float lg[NBOND];
                float m = -INFINITY;
#pragma unroll
                for (int k = 0; k < NBOND; ++k) { lg[k] = part[r][k] + b2r[k]; m = fmaxf(m, lg[k]); }
                float S = 0.f;
#pragma unroll
                for (int k = 0; k < NBOND; ++k) { lg[k] = expf(lg[k] - m); S += lg[k]; }
                float invS = 1.f / S;
#pragma unroll
                for (int k = 0; k < NBOND; ++k) out_bond[row*NBOND + k] = lg[k] * invS;
            }
        }
    }
}

extern "C" void kernel_launch(void* const* d_in, const int* in_sizes, int n_in,
                              void* d_out, int out_size, void* d_ws, size_t ws_size,
                              hipStream_t stream) {
    (void)in_sizes; (void)n_in; (void)out_size; (void)ws_size;
    const float* eta  = (const float*)d_in[0];
    const float* gum  = (const float*)d_in[1];
    const float* noi  = (const float*)d_in[2];
    const float* cw1  = (const float*)d_in[5];
    const float* cb1  = (const float*)d_in[6];
    const float* cgp  = (const float*)d_in[7];
    const float* cbe  = (const float*)d_in[8];
    const float* ca   = (const float*)d_in[9];
    const float* cw2  = (const float*)d_in[10];
    const float* cb2  = (const float*)d_in[11];
    const float* cm   = (const float*)d_in[12];
    const float* cls  = (const float*)d_in[13];
    const float* aw1  = (const float*)d_in[14];
    const float* ab1  = (const float*)d_in[15];
    const float* ag   = (const float*)d_in[16];
    const float* abe  = (const float*)d_in[17];
    const float* aa   = (const float*)d_in[18];
    const float* aw2  = (const float*)d_in[19];
    const float* ab2  = (const float*)d_in[20];
    const float* bm   = (const float*)d_in[21];
    const float* bw1  = (const float*)d_in[22];
    const float* bb1  = (const float*)d_in[23];
    const float* bg   = (const float*)d_in[24];
    const float* bbe  = (const float*)d_in[25];
    const float* ba   = (const float*)d_in[26];
    const float* bw2  = (const float*)d_in[27];
    const float* bb2  = (const float*)d_in[28];
    (void)bb1;
    float* out = (float*)d_out;
    float* ws  = (float*)d_ws;

    // ws layout (floats)
    float*          mom_z  = ws;             // 1056
    float*          mom_ef = ws + 1056;      // 1056
    float*          ascale = ws + 2112;      // 256
    float*          ashift = ws + 2368;      // 256
    float*          cpart  = ws + 2624;      // 4096 (8x512)
    unsigned short* bpack  = (unsigned short*)(ws + 6720);   // 8192 ushort
    unsigned short* apk1   = (unsigned short*)(ws + 10816);  // 8192 ushort
    unsigned short* apk2   = (unsigned short*)(ws + 14912);  // 8192 ushort
    unsigned short* wmpk   = (unsigned short*)(ws + 19008);  // 32768 ushort
    float*          h1     = ws + 35392;     // 32768
    float*          zbuf   = ws + 68160;     // 163840
    float*          efb    = ws + 232000;    // 3194880    (total ~13.1 MiB)

    k_pre       <<<dim3(233),      dim3(256), 0, stream>>>(bm, bw1, aw1, aw2, eta, cw1, cb1,
                                                           wmpk, bpack, apk1, apk2, h1, cpart, ws);
    k_edge_class<<<dim3(4*BG),     dim3(256), 0, stream>>>(h1, cpart, cgp, cbe, ca, cw2, cb2,
                                                           gum, noi, cm, cls, wmpk,
                                                           zbuf, mom_z, efb);
    k_moment    <<<dim3(MOMB+1),   dim3(256), 0, stream>>>(efb, mom_ef, mom_z,
                                                           aw1, ab1, ag, abe,
                                                           ascale, ashift, NE/32);
    k_out       <<<dim3(ATOMB + NE/BROWS4), dim3(256), 0, stream>>>(
                                                           zbuf, apk1, apk2, ab1, ascale, ashift,
                                                           aa, ab2,
                                                           efb, bpack, mom_ef, bw1, bg, bbe,
                                                           ba, bw2, bb2,
                                                           out, out + NA*NATOM);
}

// Round 15
// 79.288 us; speedup vs baseline: 1.1572x; 1.1572x over previous
//
#include <hip/hip_runtime.h>
#include <math.h>

#define BG    128                      // graphs (B)
#define NN    40                       // nodes per graph
#define AK    32                       // K (mixture comps)
#define ZD    32                       // Z latent dim
#define HIDN  256                      // HID
#define ETAD  64                       // ETA
#define NATOM 24
#define NBOND 5
#define NA    (BG*NN)                  // 5120 nodes
#define EPG   (NN*(NN-1)/2)            // 780 edges per graph
#define NE    (BG*EPG)                 // 99840 edges

typedef __attribute__((ext_vector_type(8))) short bf16x8;
typedef __attribute__((ext_vector_type(4))) float f32x4;

__device__ __forceinline__ unsigned short f2bf(float f) {
    union { float f; unsigned int u; } x; x.f = f;
    unsigned int r = x.u + 0x7fffu + ((x.u >> 16) & 1u);   // RNE
    return (unsigned short)(r >> 16);
}
__device__ __forceinline__ unsigned int pk2bf(float lo, float hi) {
    return (unsigned int)f2bf(lo) | ((unsigned int)f2bf(hi) << 16);
}

// ================= k_pre: all weight packs + class hidden + zero accums ==========
__global__ __launch_bounds__(256) void k_pre(const float* __restrict__ bm,
                                             const float* __restrict__ bw1,
                                             const float* __restrict__ aw1,
                                             const float* __restrict__ aw2,
                                             const float* __restrict__ eta,
                                             const float* __restrict__ cw1,
                                             const float* __restrict__ cb1,
                                             unsigned short* __restrict__ wmpk,
                                             unsigned short* __restrict__ bpack,
                                             unsigned short* __restrict__ apk1,
                                             unsigned short* __restrict__ apk2,
                                             float* __restrict__ h1,
                                             float* __restrict__ cpart,
                                             float* __restrict__ zacc) {
    int b = blockIdx.x, t = threadIdx.x;
    if (b < 128) {          // symmetrized Wm -> A-frag bf16
        int idx = b*256 + t;
        int d = idx >> 10;
        int Bt = (idx >> 9) & 1, ln = (idx >> 3) & 63, j = idx & 7;
        int al = Bt*16 + (ln & 15);
        int be = (ln >> 4)*8 + j;
        float v = 0.5f * (bm[d*1024 + al*32 + be] + bm[d*1024 + be*32 + al]);
        wmpk[idx] = f2bf(v);
    } else if (b < 160) {   // bw1 -> B-frag bf16
        int idx = (b - 128)*256 + t;
        int ct = idx >> 9, rem = idx & 511;
        int lane = rem >> 3, j = rem & 7;
        bpack[idx] = f2bf(bw1[((lane >> 4)*8 + j)*HIDN + ct*16 + (lane & 15)]);
    } else if (b < 192) {   // aw1 -> B-frag bf16
        int idx = (b - 160)*256 + t;
        int ct = idx >> 9, rem = idx & 511;
        int lane = rem >> 3, j = rem & 7;
        apk1[idx] = f2bf(aw1[((lane >> 4)*8 + j)*HIDN + ct*16 + (lane & 15)]);
    } else if (b < 224) {   // aw2 -> B-frag bf16 (24 cols zero-padded to 32)
        int idx = (b - 192)*256 + t;
        int f = idx >> 9, rem = idx & 511;
        int lane = rem >> 3, j = rem & 7;
        int kc = f >> 1, ot = f & 1;
        int col = ot*16 + (lane & 15);
        int k = kc*32 + (lane >> 4)*8 + j;
        apk2[idx] = (col < NATOM) ? f2bf(aw2[k*NATOM + col]) : 0;
    } else if (b < 232) {   // class h1 rows b2*16..+15, per-block stat partials
        __shared__ float es[16*ETAD];
        int b2 = b - 224;
        int r0 = b2*16;
        for (int i = t; i < 16*ETAD; i += 256) es[i] = eta[r0*ETAD + i];
        __syncthreads();
        int c = t;
        float bias = cb1[c], s = 0.f, ss = 0.f;
        for (int r = 0; r < 16; ++r) {
            float acc = bias;
#pragma unroll
            for (int a = 0; a < ETAD; ++a) acc += es[r*ETAD + a] * cw1[a*HIDN + c];
            h1[(r0 + r)*HIDN + c] = acc;
            s += acc; ss += acc*acc;
        }
        cpart[b2*512 + c] = s;
        cpart[b2*512 + 256 + c] = ss;
    } else {                // zero mom_z + mom_ef
        for (int i = t; i < 2112; i += 256) zacc[i] = 0.f;
    }
}

// ===== fused class path + edge featurizer ========================================
__global__ __launch_bounds__(256) void k_edge_class(const float* __restrict__ h1,
                                                    const float* __restrict__ cpart,
                                                    const float* __restrict__ cg,
                                                    const float* __restrict__ cbe,
                                                    const float* __restrict__ ca,
                                                    const float* __restrict__ cw2,
                                                    const float* __restrict__ cb2,
                                                    const float* __restrict__ gum,
                                                    const float* __restrict__ noise,
                                                    const float* __restrict__ cm,
                                                    const float* __restrict__ cls,
                                                    const unsigned short* __restrict__ wmpk,
                                                    float* __restrict__ z,
                                                    float* __restrict__ mom_z,
                                                    float* __restrict__ ef) {
    __shared__ float zl[NN*36];                 // 5760 B
    __shared__ float p[HIDN];
    __shared__ float vp2[256];
    __shared__ float oo[AK];
    __shared__ float lp[AK];
    __shared__ unsigned short zfrag[3*512];     // 3 KB
    __shared__ unsigned short Tf[4][3*512];     // 12 KB
    __shared__ float efl[EPG*9];                // 28 KB
    int t = threadIdx.x;
    int g = blockIdx.x >> 2, dg = blockIdx.x & 3;
    float aP = ca[0];

    // ---- class BN + W2 + log_softmax ----
    {
        float s = 0.f, ss = 0.f;
#pragma unroll
        for (int q = 0; q < 8; ++q) { s += cpart[q*512 + t]; ss += cpart[q*512 + 256 + t]; }
        float m = s * (1.0f/(float)BG);
        float v = ss * (1.0f/(float)BG) - m*m;
        float x = h1[g*HIDN + t];
        float xn = (x - m) * (1.0f/sqrtf(v + 1e-5f)) * cg[t] + cbe[t];
        p[t] = xn >= 0.f ? xn : aP*xn;
    }
    __syncthreads();
    {
        int k = t & 31, part = t >> 5;
        float acc = 0.f;
        const float* pc = &p[part*32];
        const float* wc = &cw2[(part*32)*AK + k];
#pragma unroll
        for (int c = 0; c < 32; ++c) acc += pc[c] * wc[c*AK];
        vp2[t] = acc;
    }
    __syncthreads();
    if (t < AK) {
        float acc = cb2[t];
#pragma unroll
        for (int q = 0; q < 8; ++q) acc += vp2[q*32 + t];
        oo[t] = acc;
    }
    __syncthreads();
    if (t < AK) {
        float m = -INFINITY;
#pragma unroll
        for (int k = 0; k < AK; ++k) m = fmaxf(m, oo[k]);
        float S = 0.f;
#pragma unroll
        for (int k = 0; k < AK; ++k) S += expf(oo[k] - m);
        lp[t] = oo[t] - m - logf(S);
    }
    __syncthreads();
    // ---- gumbel + z (all blocks compute; only dg==0 writes global) ----
    {
        int lane = t & 31;
#pragma unroll
        for (int nb = 0; nb < 5; ++nb) {
            int node = nb*8 + (t >> 5);
            int n = g*NN + node;
            float u = gum[(size_t)n*AK + lane];
            float x = lp[lane] - logf(-logf(u));       // TAU == 1
            float m = x;
#pragma unroll
            for (int s = 1; s < 32; s <<= 1) m = fmaxf(m, __shfl_xor(m, s, 32));
            float e = expf(x - m);
            float S = e;
#pragma unroll
            for (int s = 1; s < 32; s <<= 1) S += __shfl_xor(S, s, 32);
            unsigned long long bal = __ballot(x == m);
            unsigned grp = (unsigned)(bal >> (t & 32));
            int am = __ffs(grp) - 1;
            float best = 1.0f / S;                     // y_soft at argmax
            float cam = (1.0f - best) + best;          // exact fp replication
            float ls = cam * cls[am*ZD + lane];
            ls = fminf(fmaxf(ls, -20.0f), 30.0f);
            float zv = noise[(size_t)n*ZD + lane]*expf(ls) + cam*cm[am*ZD + lane];
            zl[node*36 + lane] = zv;
            if (dg == 0) z[(size_t)n*ZD + lane] = zv;
        }
    }
    __syncthreads();
    // ---- z-moment partials (dg==0 only) ----
    if (dg == 0) {
        int a = t >> 3, b4 = (t & 7) << 2;
        float ax = 0.f, ay = 0.f, az = 0.f, aw = 0.f;
        float mx = 0.f, my = 0.f, mz = 0.f, mw = 0.f;
        for (int r = 0; r < NN; ++r) {
            float  va = zl[r*36 + a];
            float4 vb = *(const float4*)&zl[r*36 + b4];
            ax += va*vb.x; ay += va*vb.y; az += va*vb.z; aw += va*vb.w;
            mx += vb.x;    my += vb.y;    mz += vb.z;    mw += vb.w;
        }
        atomicAdd(&mom_z[a*ZD + b4 + 0], ax);
        atomicAdd(&mom_z[a*ZD + b4 + 1], ay);
        atomicAdd(&mom_z[a*ZD + b4 + 2], az);
        atomicAdd(&mom_z[a*ZD + b4 + 3], aw);
        if (a == 0) {
            atomicAdd(&mom_z[ZD*ZD + b4 + 0], mx);
            atomicAdd(&mom_z[ZD*ZD + b4 + 1], my);
            atomicAdd(&mom_z[ZD*ZD + b4 + 2], mz);
            atomicAdd(&mom_z[ZD*ZD + b4 + 3], mw);
        }
    }
    // ---- build z MFMA frags straight from LDS ----
    if (t < 192) {
        int I = t >> 6, ln = t & 63;
        int row = I*16 + (ln & 15), c0 = (ln >> 4)*8;
        unsigned int pk[4] = {0u, 0u, 0u, 0u};
        if (row < NN) {
            float4 v0 = *(const float4*)&zl[row*36 + c0];
            float4 v1 = *(const float4*)&zl[row*36 + c0 + 4];
            pk[0] = pk2bf(v0.x, v0.y); pk[1] = pk2bf(v0.z, v0.w);
            pk[2] = pk2bf(v1.x, v1.y); pk[3] = pk2bf(v1.z, v1.w);
        }
        *(uint4*)&zfrag[(I*64 + ln)*8] = make_uint4(pk[0], pk[1], pk[2], pk[3]);
    }
    __syncthreads();

    // ---- edge featurizer via MFMA (G = Z Wsym Z^T) ----
    int w = t >> 6, lane = t & 63;
    int l15 = lane & 15, gq = lane >> 4;
    f32x4 zero4 = {0.f, 0.f, 0.f, 0.f};

    bf16x8 zf[3];
#pragma unroll
    for (int I = 0; I < 3; ++I) zf[I] = *(const bf16x8*)&zfrag[I*512 + lane*8];

    for (int dk = 0; dk < 2; ++dk) {
        int dd = w*2 + dk;
        int d  = dg*8 + dd;
        bf16x8 wA[2];
        wA[0] = *(const bf16x8*)&wmpk[(d*2 + 0)*512 + lane*8];
        wA[1] = *(const bf16x8*)&wmpk[(d*2 + 1)*512 + lane*8];

        unsigned short* tw = &Tf[w][0];
        int gqp_lo = (gq >> 1);
        int jo     = (gq & 1)*4;
#pragma unroll
        for (int Bt = 0; Bt < 2; ++Bt) {
#pragma unroll
            for (int I = 0; I < 3; ++I) {
                f32x4 c = __builtin_amdgcn_mfma_f32_16x16x32_bf16(wA[Bt], zf[I], zero4, 0, 0, 0);
                int gqp = Bt*2 + gqp_lo;
                int pos = I*512 + gqp*128 + l15*8 + jo;
                unsigned int d0 = pk2bf(c[0], c[1]);
                unsigned int d1 = pk2bf(c[2], c[3]);
                *(uint2*)&tw[pos] = make_uint2(d0, d1);
            }
        }
        __syncthreads();

        bf16x8 tf[3];
#pragma unroll
        for (int J = 0; J < 3; ++J) tf[J] = *(const bf16x8*)&Tf[w][J*512 + lane*8];

#pragma unroll
        for (int I = 0; I < 3; ++I) {
#pragma unroll
            for (int J = I; J < 3; ++J) {
                f32x4 gacc = __builtin_amdgcn_mfma_f32_16x16x32_bf16(zf[I], tf[J], zero4, 0, 0, 0);
                int j = J*16 + l15;
                if (j < NN) {
#pragma unroll
                    for (int r = 0; r < 4; ++r) {
                        int i = I*16 + 4*gq + r;
                        if (i < j) {
                            int e = i*(79 - i)/2 + (j - i - 1);
                            efl[e*9 + dd] = gacc[r];
                        }
                    }
                }
            }
        }
        __syncthreads();
    }

    size_t gE = (size_t)g * EPG;
    for (int idx = t; idx < EPG*8; idx += 256) {
        int e = idx >> 3, dd = idx & 7;
        ef[(gE + e)*ZD + dg*8 + dd] = efl[e*9 + dd];
    }
}

// ================= ef moments via MFMA (192 blocks) ==============================
#define MOMB 192
__global__ __launch_bounds__(256) void k_moment(const float* __restrict__ src,
                                                float* __restrict__ mom, int nchunks) {
    __shared__ float sm[ZD*ZD + ZD];   // 1056 floats
    int t = threadIdx.x;
    for (int i = t; i < ZD*ZD + ZD; i += 256) sm[i] = 0.f;
    __syncthreads();
    int lane = t & 63, wv = t >> 6;
    int l15 = lane & 15, g4 = lane >> 4;
    int wgid = blockIdx.x * 4 + wv;
    const int nw = MOMB * 4;
    f32x4 aII = {0,0,0,0}, aIJ = {0,0,0,0}, aJI = {0,0,0,0}, aJJ = {0,0,0,0};
    float mI = 0.f, mJ = 0.f;
    for (int ch = wgid; ch < nchunks; ch += nw) {
        const float* p = src + ((size_t)ch*32 + g4*8)*ZD + l15;
        float vI[8], vJ[8];
#pragma unroll
        for (int j = 0; j < 8; ++j) { vI[j] = p[j*ZD]; vJ[j] = p[j*ZD + 16]; }
        bf16x8 fI, fJ;
#pragma unroll
        for (int j = 0; j < 8; ++j) {
            fI[j] = (short)f2bf(vI[j]); fJ[j] = (short)f2bf(vJ[j]);
            mI += vI[j]; mJ += vJ[j];
        }
        aII = __builtin_amdgcn_mfma_f32_16x16x32_bf16(fI, fI, aII, 0, 0, 0);
        aIJ = __builtin_amdgcn_mfma_f32_16x16x32_bf16(fI, fJ, aIJ, 0, 0, 0);
        aJI = __builtin_amdgcn_mfma_f32_16x16x32_bf16(fJ, fI, aJI, 0, 0, 0);
        aJJ = __builtin_amdgcn_mfma_f32_16x16x32_bf16(fJ, fJ, aJJ, 0, 0, 0);
    }
#pragma unroll
    for (int r = 0; r < 4; ++r) {
        int row = g4*4 + r;
        atomicAdd(&sm[row*ZD + l15],             aII[r]);
        atomicAdd(&sm[row*ZD + 16 + l15],        aIJ[r]);
        atomicAdd(&sm[(16 + row)*ZD + l15],      aJI[r]);
        atomicAdd(&sm[(16 + row)*ZD + 16 + l15], aJJ[r]);
    }
    atomicAdd(&sm[ZD*ZD + l15], mI);
    atomicAdd(&sm[ZD*ZD + 16 + l15], mJ);
    __syncthreads();
    for (int i = t; i < ZD*ZD + ZD; i += 256) atomicAdd(&mom[i], sm[i]);
}

// ======= BN params from moments (blocks 0-7: atom, 8-15: bond), plain loads =======
__global__ __launch_bounds__(256) void k_prep2(const float* __restrict__ mom_z,
                                               const float* __restrict__ mom_ef,
                                               const float* __restrict__ aw1,
                                               const float* __restrict__ ab1,
                                               const float* __restrict__ ag,
                                               const float* __restrict__ abe,
                                               const float* __restrict__ bw1,
                                               const float* __restrict__ bb1,
                                               const float* __restrict__ bg,
                                               const float* __restrict__ bbe,
                                               float* __restrict__ ascale,
                                               float* __restrict__ ashift,
                                               float* __restrict__ bscale,
                                               float* __restrict__ bshift) {
    bool bond = blockIdx.x >= 8;
    const float* mom = bond ? mom_ef : mom_z;
    const float* w1  = bond ? bw1 : aw1;
    const float* b1  = bond ? bb1 : ab1;
    const float* g   = bond ? bg  : ag;
    const float* be  = bond ? bbe : abe;
    float inv_n      = bond ? (1.0f/(float)NE) : (1.0f/(float)NA);
    float* scale     = bond ? bscale : ascale;
    float* shift     = bond ? bshift : ashift;

    __shared__ float mean[ZD];
    __shared__ float cov[ZD*ZD];
    __shared__ float vp[256], mp[256];
    int t = threadIdx.x;
    if (t < ZD) mean[t] = mom[ZD*ZD + t] * inv_n;
    __syncthreads();
    for (int pp = t; pp < ZD*ZD; pp += 256) {
        int a = pp >> 5, b = pp & 31;
        cov[pp] = mom[pp] * inv_n - mean[a]*mean[b];
    }
    __syncthreads();
    int c = (blockIdx.x & 7) * 32 + (t & 31);
    int part = t >> 5;
    float wr[ZD];
#pragma unroll
    for (int b = 0; b < ZD; ++b) wr[b] = w1[b*HIDN + c];
    float var = 0.f, mh = 0.f;
#pragma unroll
    for (int q = 0; q < 4; ++q) {
        int a = part*4 + q;
        float tmp = 0.f;
#pragma unroll
        for (int b = 0; b < ZD; ++b) tmp += cov[a*ZD + b] * wr[b];
        var += tmp * wr[a];
        mh  += mean[a] * wr[a];
    }
    vp[t] = var; mp[t] = mh;
    __syncthreads();
    if (t < 32) {
        float v = 0.f, m = 0.f;
#pragma unroll
        for (int q = 0; q < 8; ++q) { v += vp[q*32 + t]; m += mp[q*32 + t]; }
        m += b1[c];
        float rs = rsqrtf(fmaxf(v, 0.f) + 1e-5f) * g[c];
        scale[c] = rs;
        shift[c] = be[c] - m * rs;
    }
}

// ====== fused output: blocks 0-79 atom MLP, blocks 80+ bond MLP (64 rows/block) ===
#define PSH 264        // halfword stride: 528B -> 2-way max on frag reads (free)
#define ATOMB (NA/64)  // 80
#define BROWS4 64
__global__ __launch_bounds__(256) void k_out(const float* __restrict__ z,
                                             const unsigned short* __restrict__ apk1,
                                             const unsigned short* __restrict__ apk2,
                                             const float* __restrict__ ab1,
                                             const float* __restrict__ ascale,
                                             const float* __restrict__ ashift,
                                             const float* __restrict__ aa,
                                             const float* __restrict__ ab2,
                                             const float* __restrict__ ef,
                                             const unsigned short* __restrict__ bpack,
                                             const float* __restrict__ bb1,
                                             const float* __restrict__ bscale,
                                             const float* __restrict__ bshift,
                                             const float* __restrict__ ba,
                                             const float* __restrict__ bw2,
                                             const float* __restrict__ bb2,
                                             float* __restrict__ out_atom,
                                             float* __restrict__ out_bond) {
    __shared__ unsigned short smu[4*16*PSH];   // 33.8 KB union
    int t = threadIdx.x;
    int w = t >> 6, lane = t & 63;
    int l15 = lane & 15, gq = lane >> 4;
    f32x4 zero4 = {0.f, 0.f, 0.f, 0.f};

    if (blockIdx.x < ATOMB) {
        // ---------------- atom path: double MFMA, wave-private LDS ----------------
        size_t r0 = (size_t)blockIdx.x * 64 + (size_t)w * 16;
        float aP = aa[0];
        unsigned short* ptw = &smu[w*16*PSH];

        const float* zp = &z[(r0 + l15)*ZD + gq*8];
        float4 z0 = *(const float4*)zp;
        float4 z1 = *(const float4*)(zp + 4);
        bf16x8 af;
        af[0] = (short)f2bf(z0.x); af[1] = (short)f2bf(z0.y);
        af[2] = (short)f2bf(z0.z); af[3] = (short)f2bf(z0.w);
        af[4] = (short)f2bf(z1.x); af[5] = (short)f2bf(z1.y);
        af[6] = (short)f2bf(z1.z); af[7] = (short)f2bf(z1.w);

#pragma unroll
        for (int ct = 0; ct < 16; ++ct) {
            bf16x8 bf = *(const bf16x8*)&apk1[ct*512 + lane*8];
            f32x4 c = __builtin_amdgcn_mfma_f32_16x16x32_bf16(af, bf, zero4, 0, 0, 0);
            int ch = ct*16 + l15;
            float sc = ascale[ch];
            float sh = ashift[ch] + ab1[ch]*sc;
#pragma unroll
            for (int r = 0; r < 4; ++r) {
                float xn = c[r]*sc + sh;
                float pv = xn >= 0.f ? xn : aP*xn;
                ptw[(4*gq + r)*PSH + ch] = f2bf(pv);
            }
        }
        // wave-private LDS: compiler lgkmcnt waits suffice, no barrier

        f32x4 o0 = zero4, o1 = zero4;
#pragma unroll
        for (int kc = 0; kc < 8; ++kc) {
            bf16x8 af2 = *(const bf16x8*)&ptw[l15*PSH + kc*32 + gq*8];
            bf16x8 b0 = *(const bf16x8*)&apk2[(kc*2 + 0)*512 + lane*8];
            bf16x8 b1 = *(const bf16x8*)&apk2[(kc*2 + 1)*512 + lane*8];
            o0 = __builtin_amdgcn_mfma_f32_16x16x32_bf16(af2, b0, o0, 0, 0, 0);
            o1 = __builtin_amdgcn_mfma_f32_16x16x32_bf16(af2, b1, o1, 0, 0, 0);
        }
#pragma unroll
        for (int r = 0; r < 4; ++r) {
            size_t row = r0 + 4*gq + r;
            out_atom[row*NATOM + l15] = o0[r] + ab2[l15];
            if (l15 < 8) out_atom[row*NATOM + 16 + l15] = o1[r] + ab2[16 + l15];
        }
        return;
    }

    // ---------------- bond path: 64 rows/block, one 16-row tile per wave ----------
    float* w2s = (float*)smu;          // 1280
    float* scs = w2s + HIDN*NBOND;     // 256
    float* shs = scs + HIDN;           // 256
    size_t r0 = (size_t)(blockIdx.x - ATOMB) * BROWS4;

    for (int i = t; i < HIDN*NBOND; i += 256) w2s[i] = bw2[i];
    { float sc = bscale[t]; scs[t] = sc; shs[t] = bshift[t] + bb1[t]*sc; }
    __syncthreads();

    float aP = ba[0];
    float b2r[NBOND];
#pragma unroll
    for (int k = 0; k < NBOND; ++k) b2r[k] = bb2[k];

    size_t rowt = r0 + (size_t)w*16;
    const float* ar = &ef[(rowt + l15)*ZD + gq*8];
    float4 a0 = *(const float4*)ar;
    float4 a1 = *(const float4*)(ar + 4);
    bf16x8 af;
    af[0] = (short)f2bf(a0.x); af[1] = (short)f2bf(a0.y);
    af[2] = (short)f2bf(a0.z); af[3] = (short)f2bf(a0.w);
    af[4] = (short)f2bf(a1.x); af[5] = (short)f2bf(a1.y);
    af[6] = (short)f2bf(a1.z); af[7] = (short)f2bf(a1.w);

    float part[4][NBOND];
#pragma unroll
    for (int r = 0; r < 4; ++r)
#pragma unroll
        for (int k = 0; k < NBOND; ++k) part[r][k] = 0.f;

#pragma unroll
    for (int h = 0; h < 2; ++h) {
        bf16x8 bfr[8];
#pragma unroll
        for (int q = 0; q < 8; ++q)
            bfr[q] = *(const bf16x8*)&bpack[(h*8 + q)*512 + lane*8];
        f32x4 acc[8];
#pragma unroll
        for (int q = 0; q < 8; ++q)
            acc[q] = __builtin_amdgcn_mfma_f32_16x16x32_bf16(af, bfr[q], zero4, 0, 0, 0);
#pragma unroll
        for (int q = 0; q < 8; ++q) {
            int c = (h*8 + q)*16 + l15;
            float sc = scs[c], sh = shs[c];
            float w0 = w2s[c*NBOND+0], w1v = w2s[c*NBOND+1], w2v = w2s[c*NBOND+2];
            float w3 = w2s[c*NBOND+3], w4 = w2s[c*NBOND+4];
#pragma unroll
            for (int r = 0; r < 4; ++r) {
                float xn = acc[q][r]*sc + sh;
                float pv = xn >= 0.f ? xn : aP*xn;
                part[r][0] += pv*w0; part[r][1] += pv*w1v; part[r][2] += pv*w2v;
                part[r][3] += pv*w3; part[r][4] += pv*w4;
            }
        }
    }

#pragma unroll
    for (int s = 1; s < 16; s <<= 1) {
#pragma unroll
        for (int r = 0; r < 4; ++r)
#pragma unroll
            for (int k = 0; k < NBOND; ++k)
                part[r][k] += __shfl_xor(part[r][k], s, 64);
    }

    if (l15 == 0) {
#pragma unroll
        for (int r = 0; r < 4; ++r) {
            size_t row = rowt + gq*4 + r;
            float lg[NBOND];
            float m = -INFINITY;
#pragma unroll
            for (int k = 0; k < NBOND; ++k) { lg[k] = part[r][k] + b2r[k]; m = fmaxf(m, lg[k]); }
            float S = 0.f;
#pragma unroll
            for (int k = 0; k < NBOND; ++k) { lg[k] = expf(lg[k] - m); S += lg[k]; }
            float invS = 1.f / S;
#pragma unroll
            for (int k = 0; k < NBOND; ++k) out_bond[row*NBOND + k] = lg[k] * invS;
        }
    }
}

extern "C" void kernel_launch(void* const* d_in, const int* in_sizes, int n_in,
                              void* d_out, int out_size, void* d_ws, size_t ws_size,
                              hipStream_t stream) {
    (void)in_sizes; (void)n_in; (void)out_size; (void)ws_size;
    const float* eta  = (const float*)d_in[0];
    const float* gum  = (const float*)d_in[1];
    const float* noi  = (const float*)d_in[2];
    const float* cw1  = (const float*)d_in[5];
    const float* cb1  = (const float*)d_in[6];
    const float* cgp  = (const float*)d_in[7];
    const float* cbe  = (const float*)d_in[8];
    const float* ca   = (const float*)d_in[9];
    const float* cw2  = (const float*)d_in[10];
    const float* cb2  = (const float*)d_in[11];
    const float* cm   = (const float*)d_in[12];
    const float* cls  = (const float*)d_in[13];
    const float* aw1  = (const float*)d_in[14];
    const float* ab1  = (const float*)d_in[15];
    const float* ag   = (const float*)d_in[16];
    const float* abe  = (const float*)d_in[17];
    const float* aa   = (const float*)d_in[18];
    const float* aw2  = (const float*)d_in[19];
    const float* ab2  = (const float*)d_in[20];
    const float* bm   = (const float*)d_in[21];
    const float* bw1  = (const float*)d_in[22];
    const float* bb1  = (const float*)d_in[23];
    const float* bg   = (const float*)d_in[24];
    const float* bbe  = (const float*)d_in[25];
    const float* ba   = (const float*)d_in[26];
    const float* bw2  = (const float*)d_in[27];
    const float* bb2  = (const float*)d_in[28];
    float* out = (float*)d_out;
    float* ws  = (float*)d_ws;

    // ws layout (floats)
    float*          mom_z  = ws;             // 1056
    float*          mom_ef = ws + 1056;      // 1056
    float*          ascale = ws + 2112;      // 256
    float*          ashift = ws + 2368;      // 256
    float*          bscale = ws + 2624;      // 256
    float*          bshift = ws + 2880;      // 256
    float*          cpart  = ws + 3136;      // 4096 (8x512)
    unsigned short* bpack  = (unsigned short*)(ws + 7232);   // 8192 ushort
    unsigned short* apk1   = (unsigned short*)(ws + 11328);  // 8192 ushort
    unsigned short* apk2   = (unsigned short*)(ws + 15424);  // 8192 ushort
    unsigned short* wmpk   = (unsigned short*)(ws + 19520);  // 32768 ushort
    float*          h1     = ws + 35904;     // 32768
    float*          zbuf   = ws + 68672;     // 163840
    float*          efb    = ws + 232512;    // 3194880    (total ~13.1 MiB)

    k_pre       <<<dim3(233),      dim3(256), 0, stream>>>(bm, bw1, aw1, aw2, eta, cw1, cb1,
                                                           wmpk, bpack, apk1, apk2, h1, cpart, ws);
    k_edge_class<<<dim3(4*BG),     dim3(256), 0, stream>>>(h1, cpart, cgp, cbe, ca, cw2, cb2,
                                                           gum, noi, cm, cls, wmpk,
                                                           zbuf, mom_z, efb);
    k_moment    <<<dim3(MOMB),     dim3(256), 0, stream>>>(efb, mom_ef, NE/32);
    k_prep2     <<<dim3(16),       dim3(256), 0, stream>>>(mom_z, mom_ef, aw1, ab1, ag, abe,
                                                           bw1, bb1, bg, bbe,
                                                           ascale, ashift, bscale, bshift);
    k_out       <<<dim3(ATOMB + NE/BROWS4), dim3(256), 0, stream>>>(
                                                           zbuf, apk1, apk2, ab1, ascale, ashift,
                                                           aa, ab2,
                                                           efb, bpack, bb1, bscale, bshift,
                                                           ba, bw2, bb2,
                                                           out, out + NA*NATOM);
}

// Round 16
// 71.796 us; speedup vs baseline: 1.2780x; 1.1043x over previous
//
#include <hip/hip_runtime.h>
#include <math.h>

#define BG    128                      // graphs (B)
#define NN    40                       // nodes per graph
#define AK    32                       // K (mixture comps)
#define ZD    32                       // Z latent dim
#define HIDN  256                      // HID
#define ETAD  64                      // ETA
#define NATOM 24
#define NBOND 5
#define NA    (BG*NN)                  // 5120 nodes
#define EPG   (NN*(NN-1)/2)            // 780 edges per graph
#define NE    (BG*EPG)                 // 99840 edges

typedef __attribute__((ext_vector_type(8))) short bf16x8;
typedef __attribute__((ext_vector_type(4))) float f32x4;

__device__ __forceinline__ unsigned short f2bf(float f) {
    union { float f; unsigned int u; } x; x.f = f;
    unsigned int r = x.u + 0x7fffu + ((x.u >> 16) & 1u);   // RNE
    return (unsigned short)(r >> 16);
}
__device__ __forceinline__ unsigned int pk2bf(float lo, float hi) {
    return (unsigned int)f2bf(lo) | ((unsigned int)f2bf(hi) << 16);
}

// ================= k_pre: all weight packs + class hidden + zero accums ==========
__global__ __launch_bounds__(256) void k_pre(const float* __restrict__ bm,
                                             const float* __restrict__ bw1,
                                             const float* __restrict__ aw1,
                                             const float* __restrict__ aw2,
                                             const float* __restrict__ eta,
                                             const float* __restrict__ cw1,
                                             const float* __restrict__ cb1,
                                             unsigned short* __restrict__ wmpk,
                                             unsigned short* __restrict__ bpack,
                                             unsigned short* __restrict__ apk1,
                                             unsigned short* __restrict__ apk2,
                                             float* __restrict__ h1,
                                             float* __restrict__ cpart,
                                             float* __restrict__ zacc) {
    int b = blockIdx.x, t = threadIdx.x;
    if (b < 128) {          // symmetrized Wm -> A-frag bf16
        int idx = b*256 + t;
        int d = idx >> 10;
        int Bt = (idx >> 9) & 1, ln = (idx >> 3) & 63, j = idx & 7;
        int al = Bt*16 + (ln & 15);
        int be = (ln >> 4)*8 + j;
        float v = 0.5f * (bm[d*1024 + al*32 + be] + bm[d*1024 + be*32 + al]);
        wmpk[idx] = f2bf(v);
    } else if (b < 160) {   // bw1 -> B-frag bf16
        int idx = (b - 128)*256 + t;
        int ct = idx >> 9, rem = idx & 511;
        int lane = rem >> 3, j = rem & 7;
        bpack[idx] = f2bf(bw1[((lane >> 4)*8 + j)*HIDN + ct*16 + (lane & 15)]);
    } else if (b < 192) {   // aw1 -> B-frag bf16
        int idx = (b - 160)*256 + t;
        int ct = idx >> 9, rem = idx & 511;
        int lane = rem >> 3, j = rem & 7;
        apk1[idx] = f2bf(aw1[((lane >> 4)*8 + j)*HIDN + ct*16 + (lane & 15)]);
    } else if (b < 224) {   // aw2 -> B-frag bf16 (24 cols zero-padded to 32)
        int idx = (b - 192)*256 + t;
        int f = idx >> 9, rem = idx & 511;
        int lane = rem >> 3, j = rem & 7;
        int kc = f >> 1, ot = f & 1;
        int col = ot*16 + (lane & 15);
        int k = kc*32 + (lane >> 4)*8 + j;
        apk2[idx] = (col < NATOM) ? f2bf(aw2[k*NATOM + col]) : 0;
    } else if (b < 232) {   // class h1 rows b2*16..+15, per-block stat partials
        __shared__ float es[16*ETAD];
        int b2 = b - 224;
        int r0 = b2*16;
        for (int i = t; i < 16*ETAD; i += 256) es[i] = eta[r0*ETAD + i];
        __syncthreads();
        int c = t;
        float bias = cb1[c], s = 0.f, ss = 0.f;
        for (int r = 0; r < 16; ++r) {
            float acc = bias;
#pragma unroll
            for (int a = 0; a < ETAD; ++a) acc += es[r*ETAD + a] * cw1[a*HIDN + c];
            h1[(r0 + r)*HIDN + c] = acc;
            s += acc; ss += acc*acc;
        }
        cpart[b2*512 + c] = s;
        cpart[b2*512 + 256 + c] = ss;
    } else {                // zero mom_z + mom_ef
        for (int i = t; i < 2112; i += 256) zacc[i] = 0.f;
    }
}

// ===== class BN + W2 + log_softmax + gumbel + z: 640 blocks (5/graph x 8 nodes) ===
__global__ __launch_bounds__(256) void k_class_z(const float* __restrict__ h1,
                                                 const float* __restrict__ cpart,
                                                 const float* __restrict__ cg,
                                                 const float* __restrict__ cbe,
                                                 const float* __restrict__ ca,
                                                 const float* __restrict__ cw2,
                                                 const float* __restrict__ cb2,
                                                 const float* __restrict__ gum,
                                                 const float* __restrict__ noise,
                                                 const float* __restrict__ cm,
                                                 const float* __restrict__ cls,
                                                 float* __restrict__ z) {
    __shared__ float p[HIDN];
    __shared__ float vp2[256];
    __shared__ float oo[AK];
    __shared__ float lp[AK];
    int t = threadIdx.x;
    int g = blockIdx.x / 5, q = blockIdx.x % 5;
    float aP = ca[0];

    {
        float s = 0.f, ss = 0.f;
#pragma unroll
        for (int qq = 0; qq < 8; ++qq) { s += cpart[qq*512 + t]; ss += cpart[qq*512 + 256 + t]; }
        float m = s * (1.0f/(float)BG);
        float v = ss * (1.0f/(float)BG) - m*m;
        float x = h1[g*HIDN + t];
        float xn = (x - m) * (1.0f/sqrtf(v + 1e-5f)) * cg[t] + cbe[t];
        p[t] = xn >= 0.f ? xn : aP*xn;
    }
    __syncthreads();
    {
        int k = t & 31, part = t >> 5;
        float acc = 0.f;
        const float* pc = &p[part*32];
        const float* wc = &cw2[(part*32)*AK + k];
#pragma unroll
        for (int c = 0; c < 32; ++c) acc += pc[c] * wc[c*AK];
        vp2[t] = acc;
    }
    __syncthreads();
    if (t < AK) {
        float acc = cb2[t];
#pragma unroll
        for (int qq = 0; qq < 8; ++qq) acc += vp2[qq*32 + t];
        oo[t] = acc;
    }
    __syncthreads();
    if (t < AK) {
        float m = -INFINITY;
#pragma unroll
        for (int k = 0; k < AK; ++k) m = fmaxf(m, oo[k]);
        float S = 0.f;
#pragma unroll
        for (int k = 0; k < AK; ++k) S += expf(oo[k] - m);
        lp[t] = oo[t] - m - logf(S);
    }
    __syncthreads();
    // this block's 8 nodes, all in one shot
    {
        int lane = t & 31;
        int node = q*8 + (t >> 5);
        int n = g*NN + node;
        float u = gum[(size_t)n*AK + lane];
        float x = lp[lane] - logf(-logf(u));       // TAU == 1
        float m = x;
#pragma unroll
        for (int s = 1; s < 32; s <<= 1) m = fmaxf(m, __shfl_xor(m, s, 32));
        float e = expf(x - m);
        float S = e;
#pragma unroll
        for (int s = 1; s < 32; s <<= 1) S += __shfl_xor(S, s, 32);
        unsigned long long bal = __ballot(x == m);
        unsigned grp = (unsigned)(bal >> (t & 32));
        int am = __ffs(grp) - 1;
        float best = 1.0f / S;                     // y_soft at argmax (exp(0)=1)
        float cam = (1.0f - best) + best;          // exact fp replication
        float ls = cam * cls[am*ZD + lane];
        ls = fminf(fmaxf(ls, -20.0f), 30.0f);
        z[(size_t)n*ZD + lane] = noise[(size_t)n*ZD + lane]*expf(ls) + cam*cm[am*ZD + lane];
    }
}

// ================= edge featurizer via MFMA (3 phases, 2 barriers) ===============
__global__ __launch_bounds__(256) void k_edge_feat(const float* __restrict__ z,
                                                   const unsigned short* __restrict__ wmpk,
                                                   float* __restrict__ ef) {
    __shared__ unsigned short zfrag[3*512];     // 3 KB
    __shared__ unsigned short Tf[4][3*512];     // 12 KB (wave-private quarters)
    __shared__ float efl[EPG*9];                // 28 KB
    int t = threadIdx.x;
    int g = blockIdx.x >> 2, dg = blockIdx.x & 3;

    if (t < 192) {
        int I = t >> 6, ln = t & 63;
        int row = I*16 + (ln & 15), c0 = (ln >> 4)*8;
        unsigned int pk[4] = {0u, 0u, 0u, 0u};
        if (row < NN) {
            const float* zp = &z[((size_t)g*NN + row)*ZD + c0];
            float4 v0 = *(const float4*)zp;
            float4 v1 = *(const float4*)(zp + 4);
            pk[0] = pk2bf(v0.x, v0.y); pk[1] = pk2bf(v0.z, v0.w);
            pk[2] = pk2bf(v1.x, v1.y); pk[3] = pk2bf(v1.z, v1.w);
        }
        *(uint4*)&zfrag[(I*64 + ln)*8] = make_uint4(pk[0], pk[1], pk[2], pk[3]);
    }
    __syncthreads();

    int w = t >> 6, lane = t & 63;
    int l15 = lane & 15, gq = lane >> 4;
    f32x4 zero4 = {0.f, 0.f, 0.f, 0.f};

    bf16x8 zf[3];
#pragma unroll
    for (int I = 0; I < 3; ++I) zf[I] = *(const bf16x8*)&zfrag[I*512 + lane*8];

    // no barriers inside: Tf[w] is wave-private; efl's dd slots are wave-exclusive
    for (int dk = 0; dk < 2; ++dk) {
        int dd = w*2 + dk;
        int d  = dg*8 + dd;
        bf16x8 wA[2];
        wA[0] = *(const bf16x8*)&wmpk[(d*2 + 0)*512 + lane*8];
        wA[1] = *(const bf16x8*)&wmpk[(d*2 + 1)*512 + lane*8];

        unsigned short* tw = &Tf[w][0];
        int gqp_lo = (gq >> 1);
        int jo     = (gq & 1)*4;
#pragma unroll
        for (int Bt = 0; Bt < 2; ++Bt) {
#pragma unroll
            for (int I = 0; I < 3; ++I) {
                f32x4 c = __builtin_amdgcn_mfma_f32_16x16x32_bf16(wA[Bt], zf[I], zero4, 0, 0, 0);
                int gqp = Bt*2 + gqp_lo;
                int pos = I*512 + gqp*128 + l15*8 + jo;
                unsigned int d0 = pk2bf(c[0], c[1]);
                unsigned int d1 = pk2bf(c[2], c[3]);
                *(uint2*)&tw[pos] = make_uint2(d0, d1);
            }
        }

        bf16x8 tf[3];
#pragma unroll
        for (int J = 0; J < 3; ++J) tf[J] = *(const bf16x8*)&Tf[w][J*512 + lane*8];

#pragma unroll
        for (int I = 0; I < 3; ++I) {
#pragma unroll
            for (int J = I; J < 3; ++J) {
                f32x4 gacc = __builtin_amdgcn_mfma_f32_16x16x32_bf16(zf[I], tf[J], zero4, 0, 0, 0);
                int j = J*16 + l15;
                if (j < NN) {
#pragma unroll
                    for (int r = 0; r < 4; ++r) {
                        int i = I*16 + 4*gq + r;
                        if (i < j) {
                            int e = i*(79 - i)/2 + (j - i - 1);
                            efl[e*9 + dd] = gacc[r];
                        }
                    }
                }
            }
        }
    }
    __syncthreads();

    size_t gE = (size_t)g * EPG;
    for (int idx = t; idx < EPG*8; idx += 256) {
        int e = idx >> 3, dd = idx & 7;
        ef[(gE + e)*ZD + dg*8 + dd] = efl[e*9 + dd];
    }
}

// ===== moments via MFMA: blocks 0-191 ef -> mom_ef; blocks 192-231 z -> mom_z =====
#define MOMB 192
#define ZMB  40
__global__ __launch_bounds__(256) void k_moment(const float* __restrict__ efsrc,
                                                const float* __restrict__ zsrc,
                                                float* __restrict__ mom_ef,
                                                float* __restrict__ mom_z) {
    __shared__ float sm[ZD*ZD + ZD];   // 1056 floats
    int t = threadIdx.x;
    bool isz = blockIdx.x >= MOMB;
    const float* src = isz ? zsrc : efsrc;
    float* mom = isz ? mom_z : mom_ef;
    int nchunks = isz ? (NA/32) : (NE/32);
    int bid = isz ? (blockIdx.x - MOMB) : blockIdx.x;
    int nw = (isz ? ZMB : MOMB) * 4;

    for (int i = t; i < ZD*ZD + ZD; i += 256) sm[i] = 0.f;
    __syncthreads();
    int lane = t & 63, wv = t >> 6;
    int l15 = lane & 15, g4 = lane >> 4;
    int wgid = bid * 4 + wv;
    f32x4 aII = {0,0,0,0}, aIJ = {0,0,0,0}, aJI = {0,0,0,0}, aJJ = {0,0,0,0};
    float mI = 0.f, mJ = 0.f;
    for (int ch = wgid; ch < nchunks; ch += nw) {
        const float* p = src + ((size_t)ch*32 + g4*8)*ZD + l15;
        float vI[8], vJ[8];
#pragma unroll
        for (int j = 0; j < 8; ++j) { vI[j] = p[j*ZD]; vJ[j] = p[j*ZD + 16]; }
        bf16x8 fI, fJ;
#pragma unroll
        for (int j = 0; j < 8; ++j) {
            fI[j] = (short)f2bf(vI[j]); fJ[j] = (short)f2bf(vJ[j]);
            mI += vI[j]; mJ += vJ[j];
        }
        aII = __builtin_amdgcn_mfma_f32_16x16x32_bf16(fI, fI, aII, 0, 0, 0);
        aIJ = __builtin_amdgcn_mfma_f32_16x16x32_bf16(fI, fJ, aIJ, 0, 0, 0);
        aJI = __builtin_amdgcn_mfma_f32_16x16x32_bf16(fJ, fI, aJI, 0, 0, 0);
        aJJ = __builtin_amdgcn_mfma_f32_16x16x32_bf16(fJ, fJ, aJJ, 0, 0, 0);
    }
#pragma unroll
    for (int r = 0; r < 4; ++r) {
        int row = g4*4 + r;
        atomicAdd(&sm[row*ZD + l15],             aII[r]);
        atomicAdd(&sm[row*ZD + 16 + l15],        aIJ[r]);
        atomicAdd(&sm[(16 + row)*ZD + l15],      aJI[r]);
        atomicAdd(&sm[(16 + row)*ZD + 16 + l15], aJJ[r]);
    }
    atomicAdd(&sm[ZD*ZD + l15], mI);
    atomicAdd(&sm[ZD*ZD + 16 + l15], mJ);
    __syncthreads();
    for (int i = t; i < ZD*ZD + ZD; i += 256) atomicAdd(&mom[i], sm[i]);
}

// ======= BN params from moments (blocks 0-7: atom, 8-15: bond), plain loads =======
__global__ __launch_bounds__(256) void k_prep2(const float* __restrict__ mom_z,
                                               const float* __restrict__ mom_ef,
                                               const float* __restrict__ aw1,
                                               const float* __restrict__ ab1,
                                               const float* __restrict__ ag,
                                               const float* __restrict__ abe,
                                               const float* __restrict__ bw1,
                                               const float* __restrict__ bb1,
                                               const float* __restrict__ bg,
                                               const float* __restrict__ bbe,
                                               float* __restrict__ ascale,
                                               float* __restrict__ ashift,
                                               float* __restrict__ bscale,
                                               float* __restrict__ bshift) {
    bool bond = blockIdx.x >= 8;
    const float* mom = bond ? mom_ef : mom_z;
    const float* w1  = bond ? bw1 : aw1;
    const float* b1  = bond ? bb1 : ab1;
    const float* g   = bond ? bg  : ag;
    const float* be  = bond ? bbe : abe;
    float inv_n      = bond ? (1.0f/(float)NE) : (1.0f/(float)NA);
    float* scale     = bond ? bscale : ascale;
    float* shift     = bond ? bshift : ashift;

    __shared__ float mean[ZD];
    __shared__ float cov[ZD*ZD];
    __shared__ float vp[256], mp[256];
    int t = threadIdx.x;
    if (t < ZD) mean[t] = mom[ZD*ZD + t] * inv_n;
    __syncthreads();
    for (int pp = t; pp < ZD*ZD; pp += 256) {
        int a = pp >> 5, b = pp & 31;
        cov[pp] = mom[pp] * inv_n - mean[a]*mean[b];
    }
    __syncthreads();
    int c = (blockIdx.x & 7) * 32 + (t & 31);
    int part = t >> 5;
    float wr[ZD];
#pragma unroll
    for (int b = 0; b < ZD; ++b) wr[b] = w1[b*HIDN + c];
    float var = 0.f, mh = 0.f;
#pragma unroll
    for (int q = 0; q < 4; ++q) {
        int a = part*4 + q;
        float tmp = 0.f;
#pragma unroll
        for (int b = 0; b < ZD; ++b) tmp += cov[a*ZD + b] * wr[b];
        var += tmp * wr[a];
        mh  += mean[a] * wr[a];
    }
    vp[t] = var; mp[t] = mh;
    __syncthreads();
    if (t < 32) {
        float v = 0.f, m = 0.f;
#pragma unroll
        for (int q = 0; q < 8; ++q) { v += vp[q*32 + t]; m += mp[q*32 + t]; }
        m += b1[c];
        float rs = rsqrtf(fmaxf(v, 0.f) + 1e-5f) * g[c];
        scale[c] = rs;
        shift[c] = be[c] - m * rs;
    }
}

// ====== fused output: blocks 0-79 atom MLP, blocks 80+ bond MLP (64 rows/block) ===
#define PSH 264        // halfword stride: 528B -> 2-way max on frag reads (free)
#define ATOMB (NA/64)  // 80
#define BROWS4 64
__global__ __launch_bounds__(256) void k_out(const float* __restrict__ z,
                                             const unsigned short* __restrict__ apk1,
                                             const unsigned short* __restrict__ apk2,
                                             const float* __restrict__ ab1,
                                             const float* __restrict__ ascale,
                                             const float* __restrict__ ashift,
                                             const float* __restrict__ aa,
                                             const float* __restrict__ ab2,
                                             const float* __restrict__ ef,
                                             const unsigned short* __restrict__ bpack,
                                             const float* __restrict__ bb1,
                                             const float* __restrict__ bscale,
                                             const float* __restrict__ bshift,
                                             const float* __restrict__ ba,
                                             const float* __restrict__ bw2,
                                             const float* __restrict__ bb2,
                                             float* __restrict__ out_atom,
                                             float* __restrict__ out_bond) {
    __shared__ unsigned short smu[4*16*PSH];   // 33.8 KB union
    int t = threadIdx.x;
    int w = t >> 6, lane = t & 63;
    int l15 = lane & 15, gq = lane >> 4;
    f32x4 zero4 = {0.f, 0.f, 0.f, 0.f};

    if (blockIdx.x < ATOMB) {
        // ---------------- atom path: double MFMA, wave-private LDS ----------------
        size_t r0 = (size_t)blockIdx.x * 64 + (size_t)w * 16;
        float aP = aa[0];
        unsigned short* ptw = &smu[w*16*PSH];

        const float* zp = &z[(r0 + l15)*ZD + gq*8];
        float4 z0 = *(const float4*)zp;
        float4 z1 = *(const float4*)(zp + 4);
        bf16x8 af;
        af[0] = (short)f2bf(z0.x); af[1] = (short)f2bf(z0.y);
        af[2] = (short)f2bf(z0.z); af[3] = (short)f2bf(z0.w);
        af[4] = (short)f2bf(z1.x); af[5] = (short)f2bf(z1.y);
        af[6] = (short)f2bf(z1.z); af[7] = (short)f2bf(z1.w);

#pragma unroll
        for (int ct = 0; ct < 16; ++ct) {
            bf16x8 bf = *(const bf16x8*)&apk1[ct*512 + lane*8];
            f32x4 c = __builtin_amdgcn_mfma_f32_16x16x32_bf16(af, bf, zero4, 0, 0, 0);
            int ch = ct*16 + l15;
            float sc = ascale[ch];
            float sh = ashift[ch] + ab1[ch]*sc;
#pragma unroll
            for (int r = 0; r < 4; ++r) {
                float xn = c[r]*sc + sh;
                float pv = xn >= 0.f ? xn : aP*xn;
                ptw[(4*gq + r)*PSH + ch] = f2bf(pv);
            }
        }
        // wave-private LDS: compiler lgkmcnt waits suffice, no barrier

        f32x4 o0 = zero4, o1 = zero4;
#pragma unroll
        for (int kc = 0; kc < 8; ++kc) {
            bf16x8 af2 = *(const bf16x8*)&ptw[l15*PSH + kc*32 + gq*8];
            bf16x8 b0 = *(const bf16x8*)&apk2[(kc*2 + 0)*512 + lane*8];
            bf16x8 b1 = *(const bf16x8*)&apk2[(kc*2 + 1)*512 + lane*8];
            o0 = __builtin_amdgcn_mfma_f32_16x16x32_bf16(af2, b0, o0, 0, 0, 0);
            o1 = __builtin_amdgcn_mfma_f32_16x16x32_bf16(af2, b1, o1, 0, 0, 0);
        }
#pragma unroll
        for (int r = 0; r < 4; ++r) {
            size_t row = r0 + 4*gq + r;
            out_atom[row*NATOM + l15] = o0[r] + ab2[l15];
            if (l15 < 8) out_atom[row*NATOM + 16 + l15] = o1[r] + ab2[16 + l15];
        }
        return;
    }

    // ---------------- bond path: 64 rows/block, one 16-row tile per wave ----------
    float* w2s = (float*)smu;          // 1280
    float* scs = w2s + HIDN*NBOND;     // 256
    float* shs = scs + HIDN;           // 256
    size_t r0 = (size_t)(blockIdx.x - ATOMB) * BROWS4;

    for (int i = t; i < HIDN*NBOND; i += 256) w2s[i] = bw2[i];
    { float sc = bscale[t]; scs[t] = sc; shs[t] = bshift[t] + bb1[t]*sc; }
    __syncthreads();

    float aP = ba[0];
    float b2r[NBOND];
#pragma unroll
    for (int k = 0; k < NBOND; ++k) b2r[k] = bb2[k];

    size_t rowt = r0 + (size_t)w*16;
    const float* ar = &ef[(rowt + l15)*ZD + gq*8];
    float4 a0 = *(const float4*)ar;
    float4 a1 = *(const float4*)(ar + 4);
    bf16x8 af;
    af[0] = (short)f2bf(a0.x); af[1] = (short)f2bf(a0.y);
    af[2] = (short)f2bf(a0.z); af[3] = (short)f2bf(a0.w);
    af[4] = (short)f2bf(a1.x); af[5] = (short)f2bf(a1.y);
    af[6] = (short)f2bf(a1.z); af[7] = (short)f2bf(a1.w);

    float part[4][NBOND];
#pragma unroll
    for (int r = 0; r < 4; ++r)
#pragma unroll
        for (int k = 0; k < NBOND; ++k) part[r][k] = 0.f;

#pragma unroll
    for (int h = 0; h < 2; ++h) {
        bf16x8 bfr[8];
#pragma unroll
        for (int q = 0; q < 8; ++q)
            bfr[q] = *(const bf16x8*)&bpack[(h*8 + q)*512 + lane*8];
        f32x4 acc[8];
#pragma unroll
        for (int q = 0; q < 8; ++q)
            acc[q] = __builtin_amdgcn_mfma_f32_16x16x32_bf16(af, bfr[q], zero4, 0, 0, 0);
#pragma unroll
        for (int q = 0; q < 8; ++q) {
            int c = (h*8 + q)*16 + l15;
            float sc = scs[c], sh = shs[c];
            float w0 = w2s[c*NBOND+0], w1v = w2s[c*NBOND+1], w2v = w2s[c*NBOND+2];
            float w3 = w2s[c*NBOND+3], w4 = w2s[c*NBOND+4];
#pragma unroll
            for (int r = 0; r < 4; ++r) {
                float xn = acc[q][r]*sc + sh;
                float pv = xn >= 0.f ? xn : aP*xn;
                part[r][0] += pv*w0; part[r][1] += pv*w1v; part[r][2] += pv*w2v;
                part[r][3] += pv*w3; part[r][4] += pv*w4;
            }
        }
    }

#pragma unroll
    for (int s = 1; s < 16; s <<= 1) {
#pragma unroll
        for (int r = 0; r < 4; ++r)
#pragma unroll
            for (int k = 0; k < NBOND; ++k)
                part[r][k] += __shfl_xor(part[r][k], s, 64);
    }

    if (l15 == 0) {
#pragma unroll
        for (int r = 0; r < 4; ++r) {
            size_t row = rowt + gq*4 + r;
            float lg[NBOND];
            float m = -INFINITY;
#pragma unroll
            for (int k = 0; k < NBOND; ++k) { lg[k] = part[r][k] + b2r[k]; m = fmaxf(m, lg[k]); }
            float S = 0.f;
#pragma unroll
            for (int k = 0; k < NBOND; ++k) { lg[k] = expf(lg[k] - m); S += lg[k]; }
            float invS = 1.f / S;
#pragma unroll
            for (int k = 0; k < NBOND; ++k) out_bond[row*NBOND + k] = lg[k] * invS;
        }
    }
}

extern "C" void kernel_launch(void* const* d_in, const int* in_sizes, int n_in,
                              void* d_out, int out_size, void* d_ws, size_t ws_size,
                              hipStream_t stream) {
    (void)in_sizes; (void)n_in; (void)out_size; (void)ws_size;
    const float* eta  = (const float*)d_in[0];
    const float* gum  = (const float*)d_in[1];
    const float* noi  = (const float*)d_in[2];
    const float* cw1  = (const float*)d_in[5];
    const float* cb1  = (const float*)d_in[6];
    const float* cgp  = (const float*)d_in[7];
    const float* cbe  = (const float*)d_in[8];
    const float* ca   = (const float*)d_in[9];
    const float* cw2  = (const float*)d_in[10];
    const float* cb2  = (const float*)d_in[11];
    const float* cm   = (const float*)d_in[12];
    const float* cls  = (const float*)d_in[13];
    const float* aw1  = (const float*)d_in[14];
    const float* ab1  = (const float*)d_in[15];
    const float* ag   = (const float*)d_in[16];
    const float* abe  = (const float*)d_in[17];
    const float* aa   = (const float*)d_in[18];
    const float* aw2  = (const float*)d_in[19];
    const float* ab2  = (const float*)d_in[20];
    const float* bm   = (const float*)d_in[21];
    const float* bw1  = (const float*)d_in[22];
    const float* bb1  = (const float*)d_in[23];
    const float* bg   = (const float*)d_in[24];
    const float* bbe  = (const float*)d_in[25];
    const float* ba   = (const float*)d_in[26];
    const float* bw2  = (const float*)d_in[27];
    const float* bb2  = (const float*)d_in[28];
    float* out = (float*)d_out;
    float* ws  = (float*)d_ws;

    // ws layout (floats)
    float*          mom_z  = ws;             // 1056
    float*          mom_ef = ws + 1056;      // 1056
    float*          ascale = ws + 2112;      // 256
    float*          ashift = ws + 2368;      // 256
    float*          bscale = ws + 2624;      // 256
    float*          bshift = ws + 2880;      // 256
    float*          cpart  = ws + 3136;      // 4096 (8x512)
    unsigned short* bpack  = (unsigned short*)(ws + 7232);   // 8192 ushort
    unsigned short* apk1   = (unsigned short*)(ws + 11328);  // 8192 ushort
    unsigned short* apk2   = (unsigned short*)(ws + 15424);  // 8192 ushort
    unsigned short* wmpk   = (unsigned short*)(ws + 19520);  // 32768 ushort
    float*          h1     = ws + 35904;     // 32768
    float*          zbuf   = ws + 68672;     // 163840
    float*          efb    = ws + 232512;    // 3194880    (total ~13.1 MiB)

    k_pre      <<<dim3(233),       dim3(256), 0, stream>>>(bm, bw1, aw1, aw2, eta, cw1, cb1,
                                                           wmpk, bpack, apk1, apk2, h1, cpart, ws);
    k_class_z  <<<dim3(5*BG),      dim3(256), 0, stream>>>(h1, cpart, cgp, cbe, ca, cw2, cb2,
                                                           gum, noi, cm, cls, zbuf);
    k_edge_feat<<<dim3(4*BG),      dim3(256), 0, stream>>>(zbuf, wmpk, efb);
    k_moment   <<<dim3(MOMB+ZMB),  dim3(256), 0, stream>>>(efb, zbuf, mom_ef, mom_z);
    k_prep2    <<<dim3(16),        dim3(256), 0, stream>>>(mom_z, mom_ef, aw1, ab1, ag, abe,
                                                           bw1, bb1, bg, bbe,
                                                           ascale, ashift, bscale, bshift);
    k_out      <<<dim3(ATOMB + NE/BROWS4), dim3(256), 0, stream>>>(
                                                           zbuf, apk1, apk2, ab1, ascale, ashift,
                                                           aa, ab2,
                                                           efb, bpack, bb1, bscale, bshift,
                                                           ba, bw2, bb2,
                                                           out, out + NA*NATOM);
}